// Round 2
// baseline (121.719 us; speedup 1.0000x reference)
//
#include <hip/hip_runtime.h>
#include <stdint.h>

#define N_TOT  8192
#define BHALF  4096
#define DDIM   128
#define NSPLIT 32

typedef short bf16x8 __attribute__((ext_vector_type(8)));
typedef float f32x4  __attribute__((ext_vector_type(4)));

__device__ __forceinline__ float ex2(float x) { return __builtin_amdgcn_exp2f(x); }

__device__ __forceinline__ unsigned short f2bf(float f) {
    uint32_t u = __builtin_bit_cast(uint32_t, f);
    u += 0x7fff + ((u >> 16) & 1);            // RNE
    return (unsigned short)(u >> 16);
}

// K1: fused cast + positives.
// zb = [z_i; z_j] in bf16 scaled by sqrt(10*log2e) so MFMA emits t = s*log2e.
// pos[i] = pos[i+B] = 10 * dot(z_i[i], z_j[i]) in fp32 (exact).
__global__ void k_prep(const float* __restrict__ zi, const float* __restrict__ zj,
                       unsigned short* __restrict__ zb, float* __restrict__ pos) {
    const float c = 3.798282440185f;          // sqrt(10*log2(e))
    int i    = blockIdx.x * 4 + (threadIdx.x >> 6);   // row pair 0..4095
    int lane = threadIdx.x & 63;
    const float2 a = *reinterpret_cast<const float2*>(zi + i * DDIM + lane * 2);
    const float2 b = *reinterpret_cast<const float2*>(zj + i * DDIM + lane * 2);
    ushort2 oa, ob;
    oa.x = f2bf(a.x * c); oa.y = f2bf(a.y * c);
    ob.x = f2bf(b.x * c); ob.y = f2bf(b.y * c);
    *reinterpret_cast<ushort2*>(zb + i * DDIM + lane * 2) = oa;
    *reinterpret_cast<ushort2*>(zb + (i + BHALF) * DDIM + lane * 2) = ob;
    float p = a.x * b.x + a.y * b.y;
    #pragma unroll
    for (int m = 32; m; m >>= 1) p += __shfl_xor(p, m, 64);
    if (lane == 0) { pos[i] = 10.f * p; pos[i + BHALF] = 10.f * p; }
}

// K2: streaming online-logsumexp over sim rows.
// Grid 1024 = 32 row-blocks x 32 col-splits. Block: 4 waves, wave = 64 rows.
// Wave tile: 64 rows x 32 cols per inner step (2 col-tiles batched into one
// softmax update). LDS is XOR-swizzled (slot = group ^ (col&7)) -> 2-way
// bank aliasing only (free) on both store and fragment-read sides.
__launch_bounds__(256, 3)
__global__ void k_main(const unsigned short* __restrict__ zb,
                       float* __restrict__ pm, float* __restrict__ pl) {
    __shared__ unsigned short lds[64 * 128];   // 16 KB, swizzled
    const int tid  = threadIdx.x;
    const int w    = tid >> 6, lane = tid & 63;
    const int q    = lane >> 4, ln = lane & 15;
    const int rb   = blockIdx.x >> 5, cs = blockIdx.x & 31;
    const int rowBase = rb * 256 + w * 64;
    const int colBase = cs * 256;

    // A fragments: 4 row-subtiles x 4 k-chunks, resident all kernel (64 VGPR).
    bf16x8 afr[4][4];
    #pragma unroll
    for (int s = 0; s < 4; ++s) {
        const unsigned short* p = zb + (rowBase + s * 16 + ln) * DDIM + q * 8;
        #pragma unroll
        for (int kc = 0; kc < 4; ++kc)
            afr[s][kc] = *reinterpret_cast<const bf16x8*>(p + kc * 32);
    }

    float m[4][4], l[4][4];
    #pragma unroll
    for (int s = 0; s < 4; ++s)
        #pragma unroll
        for (int r = 0; r < 4; ++r) { m[s][r] = -1e38f; l[s][r] = 0.f; }

    for (int ch = 0; ch < 4; ++ch) {
        // stage 64 columns (16 KB) into swizzled LDS
        #pragma unroll
        for (int it = 0; it < 4; ++it) {
            int idx  = it * 256 + tid;
            int col  = idx >> 4, g = idx & 15;
            int slot = g ^ (col & 7);
            const uint4* gp = reinterpret_cast<const uint4*>(
                zb + (colBase + ch * 64 + col) * DDIM + g * 8);
            *reinterpret_cast<uint4*>(&lds[col * 128 + slot * 8]) = *gp;
        }
        __syncthreads();

        #pragma unroll
        for (int ct2 = 0; ct2 < 2; ++ct2) {
            bf16x8 bfr[2][4];
            #pragma unroll
            for (int u = 0; u < 2; ++u) {
                int ct = ct2 * 2 + u;
                #pragma unroll
                for (int kc = 0; kc < 4; ++kc) {
                    int slot = (q + 4 * kc) ^ (ln & 7);
                    bfr[u][kc] = *reinterpret_cast<const bf16x8*>(
                        &lds[(ct * 16 + ln) * 128 + slot * 8]);
                }
            }
            const int c0 = colBase + ch * 64 + ct2 * 32;

            #pragma unroll
            for (int s = 0; s < 4; ++s) {
                f32x4 a0 = {0.f, 0.f, 0.f, 0.f}, a1 = {0.f, 0.f, 0.f, 0.f};
                #pragma unroll
                for (int kc = 0; kc < 4; ++kc) {
                    a0 = __builtin_amdgcn_mfma_f32_16x16x32_bf16(
                        afr[s][kc], bfr[0][kc], a0, 0, 0, 0);
                    a1 = __builtin_amdgcn_mfma_f32_16x16x32_bf16(
                        afr[s][kc], bfr[1][kc], a1, 0, 0, 0);
                }
                const int rowTile = rowBase + s * 16;
                if (c0 == rowTile) {                 // diag in tile 0
                    #pragma unroll
                    for (int r = 0; r < 4; ++r)
                        if (ln == q * 4 + r) a0[r] = -__builtin_inff();
                } else if (c0 + 16 == rowTile) {     // diag in tile 1
                    #pragma unroll
                    for (int r = 0; r < 4; ++r)
                        if (ln == q * 4 + r) a1[r] = -__builtin_inff();
                }
                #pragma unroll
                for (int r = 0; r < 4; ++r) {
                    float t0 = a0[r], t1 = a1[r];
                    float mo = m[s][r];
                    float mn = fmaxf(fmaxf(t0, t1), mo);
                    float sc = ex2(mo - mn);
                    float p0 = ex2(t0 - mn);
                    float p1 = ex2(t1 - mn);
                    l[s][r] = fmaf(l[s][r], sc, p0 + p1);
                    m[s][r] = mn;
                }
            }
        }
        __syncthreads();
    }

    // merge (m,l) across the 16 lanes (same quad) holding each row
    #pragma unroll
    for (int s = 0; s < 4; ++s) {
        #pragma unroll
        for (int r = 0; r < 4; ++r) {
            float mm = m[s][r], ll = l[s][r];
            #pragma unroll
            for (int msk = 1; msk < 16; msk <<= 1) {
                float om = __shfl_xor(mm, msk, 64);
                float ol = __shfl_xor(ll, msk, 64);
                float mn = fmaxf(mm, om);
                ll = ll * ex2(mm - mn) + ol * ex2(om - mn);
                mm = mn;
            }
            if (ln == 0) {
                int row = rowBase + s * 16 + q * 4 + r;
                pm[cs * N_TOT + row] = mm;
                pl[cs * N_TOT + row] = ll;
            }
        }
    }
}

// K3: per-row merge of 32 col-split partials + the extra exp(pos) term
// (pos appears both as logits[:,0] and inside neg), then block-sum.
__global__ void k_finish(const float* __restrict__ pm, const float* __restrict__ pl,
                         const float* __restrict__ pos, float* __restrict__ partial) {
    int row = blockIdx.x * 256 + threadIdx.x;
    float p  = pos[row];
    float tp = p * 1.4426950408889634f;
    float mm[NSPLIT];
    float M = tp;
    #pragma unroll
    for (int j = 0; j < NSPLIT; ++j) {
        mm[j] = pm[j * N_TOT + row];
        M = fmaxf(M, mm[j]);
    }
    float S = ex2(tp - M);
    #pragma unroll
    for (int j = 0; j < NSPLIT; ++j)
        S += pl[j * N_TOT + row] * ex2(mm[j] - M);
    float lse = (M + __log2f(S)) * 0.6931471805599453f;
    float li  = lse - p;
    #pragma unroll
    for (int msk = 32; msk; msk >>= 1) li += __shfl_xor(li, msk, 64);
    __shared__ float red[4];
    if ((threadIdx.x & 63) == 0) red[threadIdx.x >> 6] = li;
    __syncthreads();
    if (threadIdx.x == 0)
        partial[blockIdx.x] = red[0] + red[1] + red[2] + red[3];
}

__global__ void k_sum(const float* __restrict__ partial, float* __restrict__ out) {
    int lane = threadIdx.x & 63;
    float v = (lane < 32) ? partial[lane] : 0.f;
    #pragma unroll
    for (int msk = 32; msk; msk >>= 1) v += __shfl_xor(v, msk, 64);
    if (lane == 0) out[0] = v * (1.f / 8192.f);
}

extern "C" void kernel_launch(void* const* d_in, const int* in_sizes, int n_in,
                              void* d_out, int out_size, void* d_ws, size_t ws_size,
                              hipStream_t stream) {
    const float* zi = (const float*)d_in[0];
    const float* zj = (const float*)d_in[1];
    float* out = (float*)d_out;
    char* ws = (char*)d_ws;

    unsigned short* zb = (unsigned short*)ws;                        // 2 MB
    float* pos         = (float*)(ws + (size_t)2 * 1024 * 1024);     // 32 KB
    float* pm          = pos + N_TOT;                                // 1 MB
    float* pl          = pm + NSPLIT * N_TOT;                        // 1 MB
    float* partial     = pl + NSPLIT * N_TOT;                        // 128 B

    hipLaunchKernelGGL(k_prep,   dim3(1024), dim3(256), 0, stream, zi, zj, zb, pos);
    hipLaunchKernelGGL(k_main,   dim3(1024), dim3(256), 0, stream, zb, pm, pl);
    hipLaunchKernelGGL(k_finish, dim3(32),   dim3(256), 0, stream, pm, pl, pos, partial);
    hipLaunchKernelGGL(k_sum,    dim3(1),    dim3(64),  0, stream, partial, out);
}

// Round 3
// 100.926 us; speedup vs baseline: 1.2060x; 1.2060x over previous
//
#include <hip/hip_runtime.h>
#include <stdint.h>

#define N_TOT  8192
#define BHALF  4096
#define DDIM   128
#define NSPLIT 32

typedef short bf16x8 __attribute__((ext_vector_type(8)));
typedef float f32x4  __attribute__((ext_vector_type(4)));

__device__ __forceinline__ float ex2(float x) { return __builtin_amdgcn_exp2f(x); }

__device__ __forceinline__ unsigned short f2bf(float f) {
    uint32_t u = __builtin_bit_cast(uint32_t, f);
    u += 0x7fff + ((u >> 16) & 1);            // RNE
    return (unsigned short)(u >> 16);
}

// K1: fused cast + positives.
// zb = [z_i; z_j] in bf16 scaled by sqrt(10*log2e) so MFMA emits t = s*log2e.
// pos[i] = pos[i+B] = 10 * dot(z_i[i], z_j[i]) in fp32 (exact).
__global__ void k_prep(const float* __restrict__ zi, const float* __restrict__ zj,
                       unsigned short* __restrict__ zb, float* __restrict__ pos) {
    const float c = 3.798282440185f;          // sqrt(10*log2(e))
    int i    = blockIdx.x * 4 + (threadIdx.x >> 6);   // row pair 0..4095
    int lane = threadIdx.x & 63;
    const float2 a = *reinterpret_cast<const float2*>(zi + i * DDIM + lane * 2);
    const float2 b = *reinterpret_cast<const float2*>(zj + i * DDIM + lane * 2);
    ushort2 oa, ob;
    oa.x = f2bf(a.x * c); oa.y = f2bf(a.y * c);
    ob.x = f2bf(b.x * c); ob.y = f2bf(b.y * c);
    *reinterpret_cast<ushort2*>(zb + i * DDIM + lane * 2) = oa;
    *reinterpret_cast<ushort2*>(zb + (i + BHALF) * DDIM + lane * 2) = ob;
    float p = a.x * b.x + a.y * b.y;
    #pragma unroll
    for (int m = 32; m; m >>= 1) p += __shfl_xor(p, m, 64);
    if (lane == 0) { pos[i] = 10.f * p; pos[i + BHALF] = 10.f * p; }
}

// K2: streaming online-logsumexp over sim rows.
// Grid 1024 = 32 row-blocks x 32 col-splits. Block: 8 waves of 32 rows each
// (512 threads, 256 rows/block). Single 16-col tile per softmax update.
// Register budget kept under the 128-VGPR cliff so 4 waves/SIMD fit:
// afr 32 + bfr 16 + m/l 16 + acc 4 + addr ~ 100.
__launch_bounds__(512, 4)
__global__ void k_main(const unsigned short* __restrict__ zb,
                       float* __restrict__ pm, float* __restrict__ pl) {
    __shared__ unsigned short lds[64 * 128];   // 16 KB, XOR-swizzled
    const int tid  = threadIdx.x;
    const int w    = tid >> 6, lane = tid & 63;
    const int q    = lane >> 4, ln = lane & 15;
    const int rb   = blockIdx.x >> 5, cs = blockIdx.x & 31;
    const int rowBase = rb * 256 + w * 32;
    const int colBase = cs * 256;

    // A fragments: 2 row-subtiles x 4 k-chunks, resident all kernel (32 VGPR).
    bf16x8 afr[2][4];
    #pragma unroll
    for (int s = 0; s < 2; ++s) {
        const unsigned short* p = zb + (rowBase + s * 16 + ln) * DDIM + q * 8;
        #pragma unroll
        for (int kc = 0; kc < 4; ++kc)
            afr[s][kc] = *reinterpret_cast<const bf16x8*>(p + kc * 32);
    }

    float m[2][4], l[2][4];
    #pragma unroll
    for (int s = 0; s < 2; ++s)
        #pragma unroll
        for (int r = 0; r < 4; ++r) { m[s][r] = -1e38f; l[s][r] = 0.f; }

    for (int ch = 0; ch < 4; ++ch) {
        // stage 64 columns (16 KB) into swizzled LDS: 1024 uint4, 512 threads
        #pragma unroll
        for (int it = 0; it < 2; ++it) {
            int idx  = it * 512 + tid;
            int col  = idx >> 4, g = idx & 15;
            int slot = g ^ (col & 7);
            const uint4* gp = reinterpret_cast<const uint4*>(
                zb + (colBase + ch * 64 + col) * DDIM + g * 8);
            *reinterpret_cast<uint4*>(&lds[col * 128 + slot * 8]) = *gp;
        }
        __syncthreads();

        #pragma unroll
        for (int ct = 0; ct < 4; ++ct) {
            bf16x8 bfr[4];
            #pragma unroll
            for (int kc = 0; kc < 4; ++kc) {
                int slot = (q + 4 * kc) ^ (ln & 7);
                bfr[kc] = *reinterpret_cast<const bf16x8*>(
                    &lds[(ct * 16 + ln) * 128 + slot * 8]);
            }
            const int colTile = colBase + ch * 64 + ct * 16;

            #pragma unroll
            for (int s = 0; s < 2; ++s) {
                f32x4 acc = {0.f, 0.f, 0.f, 0.f};
                #pragma unroll
                for (int kc = 0; kc < 4; ++kc)
                    acc = __builtin_amdgcn_mfma_f32_16x16x32_bf16(
                        afr[s][kc], bfr[kc], acc, 0, 0, 0);
                if (colTile == rowBase + s * 16) {   // diagonal tile: mask
                    #pragma unroll
                    for (int r = 0; r < 4; ++r)
                        if (ln == q * 4 + r) acc[r] = -__builtin_inff();
                }
                #pragma unroll
                for (int r = 0; r < 4; ++r) {
                    float t  = acc[r];               // = s_ij * log2(e)
                    float mo = m[s][r];
                    float mn = fmaxf(mo, t);
                    float pv = ex2(t - mn);
                    float sc = ex2(mo - mn);
                    l[s][r] = fmaf(l[s][r], sc, pv);
                    m[s][r] = mn;
                }
            }
        }
        __syncthreads();
    }

    // merge (m,l) across the 16 lanes (same quad) holding each row
    #pragma unroll
    for (int s = 0; s < 2; ++s) {
        #pragma unroll
        for (int r = 0; r < 4; ++r) {
            float mm = m[s][r], ll = l[s][r];
            #pragma unroll
            for (int msk = 1; msk < 16; msk <<= 1) {
                float om = __shfl_xor(mm, msk, 64);
                float ol = __shfl_xor(ll, msk, 64);
                float mn = fmaxf(mm, om);
                ll = ll * ex2(mm - mn) + ol * ex2(om - mn);
                mm = mn;
            }
            if (ln == 0) {
                int row = rowBase + s * 16 + q * 4 + r;
                pm[cs * N_TOT + row] = mm;
                pl[cs * N_TOT + row] = ll;
            }
        }
    }
}

// K3: per-row merge of 32 col-split partials + the extra exp(pos) term
// (pos appears both as logits[:,0] and inside neg), then block-sum.
__global__ void k_finish(const float* __restrict__ pm, const float* __restrict__ pl,
                         const float* __restrict__ pos, float* __restrict__ partial) {
    int row = blockIdx.x * 256 + threadIdx.x;
    float p  = pos[row];
    float tp = p * 1.4426950408889634f;
    float mm[NSPLIT];
    float M = tp;
    #pragma unroll
    for (int j = 0; j < NSPLIT; ++j) {
        mm[j] = pm[j * N_TOT + row];
        M = fmaxf(M, mm[j]);
    }
    float S = ex2(tp - M);
    #pragma unroll
    for (int j = 0; j < NSPLIT; ++j)
        S += pl[j * N_TOT + row] * ex2(mm[j] - M);
    float lse = (M + __log2f(S)) * 0.6931471805599453f;
    float li  = lse - p;
    #pragma unroll
    for (int msk = 32; msk; msk >>= 1) li += __shfl_xor(li, msk, 64);
    __shared__ float red[4];
    if ((threadIdx.x & 63) == 0) red[threadIdx.x >> 6] = li;
    __syncthreads();
    if (threadIdx.x == 0)
        partial[blockIdx.x] = red[0] + red[1] + red[2] + red[3];
}

__global__ void k_sum(const float* __restrict__ partial, float* __restrict__ out) {
    int lane = threadIdx.x & 63;
    float v = (lane < 32) ? partial[lane] : 0.f;
    #pragma unroll
    for (int msk = 32; msk; msk >>= 1) v += __shfl_xor(v, msk, 64);
    if (lane == 0) out[0] = v * (1.f / 8192.f);
}

extern "C" void kernel_launch(void* const* d_in, const int* in_sizes, int n_in,
                              void* d_out, int out_size, void* d_ws, size_t ws_size,
                              hipStream_t stream) {
    const float* zi = (const float*)d_in[0];
    const float* zj = (const float*)d_in[1];
    float* out = (float*)d_out;
    char* ws = (char*)d_ws;

    unsigned short* zb = (unsigned short*)ws;                        // 2 MB
    float* pos         = (float*)(ws + (size_t)2 * 1024 * 1024);     // 32 KB
    float* pm          = pos + N_TOT;                                // 1 MB
    float* pl          = pm + NSPLIT * N_TOT;                        // 1 MB
    float* partial     = pl + NSPLIT * N_TOT;                        // 128 B

    hipLaunchKernelGGL(k_prep,   dim3(1024), dim3(256), 0, stream, zi, zj, zb, pos);
    hipLaunchKernelGGL(k_main,   dim3(1024), dim3(512), 0, stream, zb, pm, pl);
    hipLaunchKernelGGL(k_finish, dim3(32),   dim3(256), 0, stream, pm, pl, pos, partial);
    hipLaunchKernelGGL(k_sum,    dim3(1),    dim3(64),  0, stream, partial, out);
}

// Round 4
// 99.928 us; speedup vs baseline: 1.2181x; 1.0100x over previous
//
#include <hip/hip_runtime.h>
#include <hip/hip_bf16.h>
#include <stdint.h>

#define N_TOT  8192
#define BHALF  4096
#define DDIM   128
#define NSPLIT 16

typedef short bf16x8 __attribute__((ext_vector_type(8)));
typedef float f32x4  __attribute__((ext_vector_type(4)));

__device__ __forceinline__ float ex2(float x) { return __builtin_amdgcn_exp2f(x); }

#define SCALE_C 3.798282440185f   /* sqrt(10*log2(e)): MFMA emits t = s*log2e */

__device__ __forceinline__ ushort2 cvt2(float a, float b) {
    __hip_bfloat162 h = __float22bfloat162_rn(make_float2(a, b));
    return *reinterpret_cast<ushort2*>(&h);
}

__device__ __forceinline__ bf16x8 cvt8(float4 lo, float4 hi) {
    union { bf16x8 v; ushort2 u[4]; } r;
    r.u[0] = cvt2(lo.x * SCALE_C, lo.y * SCALE_C);
    r.u[1] = cvt2(lo.z * SCALE_C, lo.w * SCALE_C);
    r.u[2] = cvt2(hi.x * SCALE_C, hi.y * SCALE_C);
    r.u[3] = cvt2(hi.z * SCALE_C, hi.w * SCALE_C);
    return r.v;
}

struct StageRegs { float4 v[4]; };

__device__ __forceinline__ StageRegs stage_load(const float* __restrict__ zi,
                                                const float* __restrict__ zj,
                                                int colBase, int ch, int tid) {
    StageRegs s;
    #pragma unroll
    for (int it = 0; it < 2; ++it) {
        int idx  = it * 512 + tid;
        int col  = idx >> 4, g = idx & 15;
        int gcol = colBase + ch * 64 + col;
        const float* cp = (gcol < BHALF) ? zi + gcol * DDIM
                                         : zj + (gcol - BHALF) * DDIM;
        s.v[it * 2]     = *reinterpret_cast<const float4*>(cp + g * 8);
        s.v[it * 2 + 1] = *reinterpret_cast<const float4*>(cp + g * 8 + 4);
    }
    return s;
}

__device__ __forceinline__ void stage_write(const StageRegs& s, int tid,
                                            unsigned short* buf) {
    #pragma unroll
    for (int it = 0; it < 2; ++it) {
        int idx  = it * 512 + tid;
        int col  = idx >> 4, g = idx & 15;
        int slot = g ^ (col & 7);                  // XOR bank swizzle
        *reinterpret_cast<bf16x8*>(&buf[col * 128 + slot * 8]) =
            cvt8(s.v[it * 2], s.v[it * 2 + 1]);
    }
}

// K1: streaming online-logsumexp over sim = (z z^T)/T rows, bf16 MFMA.
// Grid 512 = 32 row-blocks x 16 col-splits (512 cols each). Block: 8 waves
// of 32 rows. Inner: 2 col-tiles batched into one softmax rescale.
// Double-buffered LDS, one barrier per 64-col chunk.
__launch_bounds__(512, 4)
__global__ void k_main(const float* __restrict__ zi, const float* __restrict__ zj,
                       float* __restrict__ pm, float* __restrict__ pl,
                       float* __restrict__ out) {
    if (blockIdx.x == 0 && threadIdx.x == 0) out[0] = 0.f;  // init for k_finish atomics
    __shared__ unsigned short lds[2][64 * 128];   // 2 x 16 KB
    const int tid = threadIdx.x;
    const int w = tid >> 6, lane = tid & 63;
    const int q = lane >> 4, ln = lane & 15;
    const int rb = blockIdx.x >> 4, cs = blockIdx.x & 15;
    const int rowBase = rb * 256 + w * 32;
    const int colBase = cs * 512;

    // A fragments: 2 row-subtiles x 4 k-chunks, cast from fp32 (32 VGPR).
    bf16x8 afr[2][4];
    #pragma unroll
    for (int s = 0; s < 2; ++s) {
        int row = rowBase + s * 16 + ln;
        const float* rp = (row < BHALF) ? zi + row * DDIM
                                        : zj + (row - BHALF) * DDIM;
        #pragma unroll
        for (int kc = 0; kc < 4; ++kc) {
            float4 lo = *reinterpret_cast<const float4*>(rp + kc * 32 + q * 8);
            float4 hi = *reinterpret_cast<const float4*>(rp + kc * 32 + q * 8 + 4);
            afr[s][kc] = cvt8(lo, hi);
        }
    }

    float m[2][4], l[2][4];
    #pragma unroll
    for (int s = 0; s < 2; ++s)
        #pragma unroll
        for (int r = 0; r < 4; ++r) { m[s][r] = -1e38f; l[s][r] = 0.f; }

    StageRegs sr = stage_load(zi, zj, colBase, 0, tid);
    stage_write(sr, tid, lds[0]);
    __syncthreads();

    for (int ch = 0; ch < 8; ++ch) {
        const unsigned short* buf = lds[ch & 1];
        if (ch < 7) sr = stage_load(zi, zj, colBase, ch + 1, tid);  // prefetch

        #pragma unroll
        for (int ct2 = 0; ct2 < 2; ++ct2) {
            f32x4 acc[2][2];
            #pragma unroll
            for (int s = 0; s < 2; ++s)
                #pragma unroll
                for (int u = 0; u < 2; ++u) acc[s][u] = (f32x4){0.f, 0.f, 0.f, 0.f};

            #pragma unroll
            for (int u = 0; u < 2; ++u) {          // bfr transient: 16 VGPR
                int ct = ct2 * 2 + u;
                bf16x8 bfr[4];
                #pragma unroll
                for (int kc = 0; kc < 4; ++kc) {
                    int slot = (q + 4 * kc) ^ (ln & 7);
                    bfr[kc] = *reinterpret_cast<const bf16x8*>(
                        &buf[(ct * 16 + ln) * 128 + slot * 8]);
                }
                #pragma unroll
                for (int s = 0; s < 2; ++s)
                    #pragma unroll
                    for (int kc = 0; kc < 4; ++kc)
                        acc[s][u] = __builtin_amdgcn_mfma_f32_16x16x32_bf16(
                            afr[s][kc], bfr[kc], acc[s][u], 0, 0, 0);
            }

            const int c0 = colBase + ch * 64 + ct2 * 32;
            #pragma unroll
            for (int s = 0; s < 2; ++s) {
                const int rt = rowBase + s * 16;
                if (c0 == rt) {                      // diag in tile u=0
                    #pragma unroll
                    for (int r = 0; r < 4; ++r)
                        if (ln == q * 4 + r) acc[s][0][r] = -__builtin_inff();
                } else if (c0 + 16 == rt) {          // diag in tile u=1
                    #pragma unroll
                    for (int r = 0; r < 4; ++r)
                        if (ln == q * 4 + r) acc[s][1][r] = -__builtin_inff();
                }
                #pragma unroll
                for (int r = 0; r < 4; ++r) {        // batched online update
                    float t0 = acc[s][0][r], t1 = acc[s][1][r];
                    float mo = m[s][r];
                    float mn = fmaxf(fmaxf(t0, t1), mo);
                    float sc = ex2(mo - mn);
                    float pv = ex2(t0 - mn) + ex2(t1 - mn);
                    l[s][r] = fmaf(l[s][r], sc, pv);
                    m[s][r] = mn;
                }
            }
        }

        if (ch < 7) stage_write(sr, tid, lds[(ch + 1) & 1]);
        __syncthreads();
    }

    // merge (m,l) across the 16 lanes (same quad) holding each row
    #pragma unroll
    for (int s = 0; s < 2; ++s) {
        #pragma unroll
        for (int r = 0; r < 4; ++r) {
            float mm = m[s][r], ll = l[s][r];
            #pragma unroll
            for (int msk = 1; msk < 16; msk <<= 1) {
                float om = __shfl_xor(mm, msk, 64);
                float ol = __shfl_xor(ll, msk, 64);
                float mn = fmaxf(mm, om);
                ll = ll * ex2(mm - mn) + ol * ex2(om - mn);
                mm = mn;
            }
            if (ln == 0) {
                int row = rowBase + s * 16 + q * 4 + r;
                pm[cs * N_TOT + row] = mm;
                pl[cs * N_TOT + row] = ll;
            }
        }
    }
}

// K2: per-row merge of 16 col-split partials, pos computed inline (fp32
// exact), extra exp(pos) term (pos appears in logits[:,0] AND inside neg),
// block-reduce, atomicAdd into out (zeroed by k_main).
__global__ void k_finish(const float* __restrict__ zi, const float* __restrict__ zj,
                         const float* __restrict__ pm, const float* __restrict__ pl,
                         float* __restrict__ out) {
    int row = blockIdx.x * 256 + threadIdx.x;
    int pr  = row & (BHALF - 1);
    const float4* a = reinterpret_cast<const float4*>(zi + pr * DDIM);
    const float4* b = reinterpret_cast<const float4*>(zj + pr * DDIM);
    float acc = 0.f;
    #pragma unroll
    for (int k = 0; k < 32; ++k) {
        float4 x = a[k], y = b[k];
        acc += x.x * y.x + x.y * y.y + x.z * y.z + x.w * y.w;
    }
    float p  = 10.f * acc;
    float tp = p * 1.4426950408889634f;
    float mm[NSPLIT];
    float M = tp;
    #pragma unroll
    for (int j = 0; j < NSPLIT; ++j) {
        mm[j] = pm[j * N_TOT + row];
        M = fmaxf(M, mm[j]);
    }
    float S = ex2(tp - M);
    #pragma unroll
    for (int j = 0; j < NSPLIT; ++j)
        S += pl[j * N_TOT + row] * ex2(mm[j] - M);
    float lse = (M + __log2f(S)) * 0.6931471805599453f;
    float li  = lse - p;
    #pragma unroll
    for (int msk = 32; msk; msk >>= 1) li += __shfl_xor(li, msk, 64);
    __shared__ float red[4];
    if ((threadIdx.x & 63) == 0) red[threadIdx.x >> 6] = li;
    __syncthreads();
    if (threadIdx.x == 0)
        atomicAdd(out, (red[0] + red[1] + red[2] + red[3]) * (1.f / 8192.f));
}

extern "C" void kernel_launch(void* const* d_in, const int* in_sizes, int n_in,
                              void* d_out, int out_size, void* d_ws, size_t ws_size,
                              hipStream_t stream) {
    const float* zi = (const float*)d_in[0];
    const float* zj = (const float*)d_in[1];
    float* out = (float*)d_out;
    char* ws = (char*)d_ws;

    float* pm = (float*)ws;                        // 16*8192*4 = 512 KB
    float* pl = pm + NSPLIT * N_TOT;               // 512 KB

    hipLaunchKernelGGL(k_main,   dim3(512), dim3(512), 0, stream, zi, zj, pm, pl, out);
    hipLaunchKernelGGL(k_finish, dim3(32),  dim3(256), 0, stream, zi, zj, pm, pl, out);
}